// Round 2
// baseline (8594.576 us; speedup 1.0000x reference)
//
#include <hip/hip_runtime.h>

// GINEEncoderBlock — round 1: fix in-place GEMM race.
// Round-0 bug: 2-D tiled GEMM wrote column slices of rows that OTHER blocks
// (different blockIdx.y) still needed to read at full K — in-place edge/node
// GEMM corrupted data. Fix: 1-D row-tile blocks computing the FULL 256-wide
// output row, so each block is the sole reader+writer of its rows.

#define D 256
#define BN_EPS 1e-5f

// ---------------------------------------------------------------- scatter ----
// one wave (64 lanes) per edge; lane covers 4 floats (float4) of the 256-row.
__global__ __launch_bounds__(256) void scatter_msg(
    const float* __restrict__ x, const float* __restrict__ e,
    const int* __restrict__ src, const int* __restrict__ dst,
    float* __restrict__ aggr, int E)
{
    int ed = blockIdx.x * 4 + (threadIdx.x >> 6);
    if (ed >= E) return;
    int lane = threadIdx.x & 63;
    int s = src[ed], d = dst[ed];
    float4 ev = ((const float4*)(e + (size_t)ed * D))[lane];
    float4 xv = ((const float4*)(x + (size_t)s * D))[lane];
    float4 m;
    m.x = fmaxf(ev.x + xv.x, 0.f);
    m.y = fmaxf(ev.y + xv.y, 0.f);
    m.z = fmaxf(ev.z + xv.z, 0.f);
    m.w = fmaxf(ev.w + xv.w, 0.f);
    float* ap = aggr + (size_t)d * D + lane * 4;
    atomicAdd(ap + 0, m.x);
    atomicAdd(ap + 1, m.y);
    atomicAdd(ap + 2, m.z);
    atomicAdd(ap + 3, m.w);
}

// ------------------------------------------------------------------- GEMM ----
// Each block: 64 rows x FULL 256 cols. out[r,:] = relu((A[r,:](+aggr[r,:]))@W
// + bias)(+init[r,:]). In-place safe: this block is the only reader of its
// rows. 256 thr = 16x16; thread computes 4 rows x 16 cols. K-chunk = 16.
template<bool HAS_AGGR, bool ADD_INIT>
__global__ __launch_bounds__(256) void gemm_rowfull(
    const float* A, const float* __restrict__ aggr,
    const float* __restrict__ W, const float* __restrict__ bias,
    const float* __restrict__ init, float* out, int rows)
{
    __shared__ float As[16][68];    // [k][m], +4 pad: float4-aligned, <=2-way banks
    __shared__ float Bs[16][260];   // [k][n], +4 pad: kills 4-way write conflict

    const int tid = threadIdx.x;
    const int m0 = blockIdx.x * 64;
    const int tx = tid & 15;              // col group: cols tx*16 .. tx*16+15
    const int ty = tid >> 4;              // row group: rows ty*4 .. ty*4+3

    const int arow = tid >> 2;            // 0..63
    const int ak4  = (tid & 3) << 2;      // 0,4,8,12
    const int bk   = tid >> 4;            // 0..15
    const int bn4  = (tid & 15) << 2;     // 0..60

    float acc[4][16];
#pragma unroll
    for (int i = 0; i < 4; ++i)
#pragma unroll
        for (int j = 0; j < 16; ++j) acc[i][j] = 0.f;

    for (int k0 = 0; k0 < D; k0 += 16) {
        // stage A-chunk (transposed) : 64 rows x 16 k
        float4 av = make_float4(0.f, 0.f, 0.f, 0.f);
        int gr = m0 + arow;
        if (gr < rows) {
            av = *(const float4*)(A + (size_t)gr * D + k0 + ak4);
            if (HAS_AGGR) {
                float4 g = *(const float4*)(aggr + (size_t)gr * D + k0 + ak4);
                av.x += g.x; av.y += g.y; av.z += g.z; av.w += g.w;
            }
        }
        As[ak4 + 0][arow] = av.x;
        As[ak4 + 1][arow] = av.y;
        As[ak4 + 2][arow] = av.z;
        As[ak4 + 3][arow] = av.w;
        // stage B-chunk: 16 k x 256 n  (4 passes of 64 cols)
#pragma unroll
        for (int c = 0; c < 4; ++c)
            *(float4*)&Bs[bk][c * 64 + bn4] =
                *(const float4*)(W + (size_t)(k0 + bk) * D + c * 64 + bn4);
        __syncthreads();
#pragma unroll
        for (int k = 0; k < 16; ++k) {
            float4 a4 = *(const float4*)&As[k][ty << 2];
            float a[4] = {a4.x, a4.y, a4.z, a4.w};
#pragma unroll
            for (int jc = 0; jc < 4; ++jc) {
                float4 b4 = *(const float4*)&Bs[k][(tx << 4) + (jc << 2)];
#pragma unroll
                for (int i = 0; i < 4; ++i) {
                    acc[i][jc * 4 + 0] += a[i] * b4.x;
                    acc[i][jc * 4 + 1] += a[i] * b4.y;
                    acc[i][jc * 4 + 2] += a[i] * b4.z;
                    acc[i][jc * 4 + 3] += a[i] * b4.w;
                }
            }
        }
        __syncthreads();
    }

    // epilogue: bias + relu (+init), write 4 rows x 16 cols
#pragma unroll
    for (int jc = 0; jc < 4; ++jc) {
        int col = (tx << 4) + (jc << 2);
        float4 bias4 = *(const float4*)(bias + col);
#pragma unroll
        for (int i = 0; i < 4; ++i) {
            int gr = m0 + (ty << 2) + i;
            if (gr < rows) {
                float4 o;
                o.x = fmaxf(acc[i][jc * 4 + 0] + bias4.x, 0.f);
                o.y = fmaxf(acc[i][jc * 4 + 1] + bias4.y, 0.f);
                o.z = fmaxf(acc[i][jc * 4 + 2] + bias4.z, 0.f);
                o.w = fmaxf(acc[i][jc * 4 + 3] + bias4.w, 0.f);
                if (ADD_INIT) {
                    float4 iv = *(const float4*)(init + (size_t)gr * D + col);
                    o.x += iv.x; o.y += iv.y; o.z += iv.z; o.w += iv.w;
                }
                *(float4*)(out + (size_t)gr * D + col) = o;
            }
        }
    }
}

// --------------------------------------------------------------------- BN ----
__global__ __launch_bounds__(256) void bn_stats_kernel(
    const float* __restrict__ x, float* __restrict__ stats, int N)
{
    int col = threadIdx.x;
    float s = 0.f, s2 = 0.f;
    for (int r = blockIdx.x; r < N; r += gridDim.x) {
        float v = x[(size_t)r * D + col];
        s += v; s2 += v * v;
    }
    atomicAdd(&stats[col], s);
    atomicAdd(&stats[D + col], s2);
}

__global__ __launch_bounds__(256) void bn_apply_kernel(
    float* __restrict__ x, const float* __restrict__ stats,
    const float* __restrict__ gamma, const float* __restrict__ beta, int N)
{
    int col = threadIdx.x;
    float inv_n = 1.f / (float)N;
    float mean = stats[col] * inv_n;
    float var  = stats[D + col] * inv_n - mean * mean;
    float scale = gamma[col] * rsqrtf(var + BN_EPS);
    float shift = beta[col] - mean * scale;
    for (int r = blockIdx.x; r < N; r += gridDim.x) {
        size_t idx = (size_t)r * D + col;
        x[idx] = x[idx] * scale + shift;
    }
}

// ----------------------------------------------------------------- launch ----
extern "C" void kernel_launch(void* const* d_in, const int* in_sizes, int n_in,
                              void* d_out, int out_size, void* d_ws, size_t ws_size,
                              hipStream_t stream)
{
    const float* node_feat = (const float*)d_in[0];
    float*       e         = (float*)d_in[1];   // updated in place (harness restores)
    const int*   src       = (const int*)d_in[2];
    const int*   dst       = (const int*)d_in[3];
    const float* W_conv    = (const float*)d_in[4];
    const float* b_conv    = (const float*)d_in[5];
    const float* W_edge    = (const float*)d_in[6];
    const float* b_edge    = (const float*)d_in[7];
    const float* gamma     = (const float*)d_in[8];
    const float* beta      = (const float*)d_in[9];
    float*       out       = (float*)d_out;

    const int N = in_sizes[0] / D;
    const int E = in_sizes[2];
    const int L = in_sizes[5] / D;   // b_conv is [L, D]

    float* x     = (float*)d_ws;                 // N*D
    float* aggr  = x + (size_t)N * D;            // N*D
    float* stats = aggr + (size_t)N * D;         // 2*D

    int nodeBlocks = (N + 63) / 64;
    int edgeBlocks = (E + 63) / 64;
    int scatterBlocks = (E + 3) / 4;

    const float* xin = node_feat;
    for (int i = 0; i < L; ++i) {
        hipMemsetAsync(aggr, 0, (size_t)N * D * sizeof(float), stream);
        scatter_msg<<<scatterBlocks, 256, 0, stream>>>(xin, e, src, dst, aggr, E);
        gemm_rowfull<true, false><<<nodeBlocks, 256, 0, stream>>>(
            xin, aggr, W_conv + (size_t)i * D * D, b_conv + (size_t)i * D,
            nullptr, x, N);
        hipMemsetAsync(stats, 0, 2 * D * sizeof(float), stream);
        bn_stats_kernel<<<512, 256, 0, stream>>>(x, stats, N);
        bn_apply_kernel<<<1024, 256, 0, stream>>>(
            x, stats, gamma + (size_t)i * D, beta + (size_t)i * D, N);
        gemm_rowfull<false, false><<<edgeBlocks, 256, 0, stream>>>(
            e, nullptr, W_edge + (size_t)i * D * D, b_edge + (size_t)i * D,
            nullptr, e, E);
        xin = x;
    }

    // final conv: layer L-1 weights on current (x, e), then + node_feat
    hipMemsetAsync(aggr, 0, (size_t)N * D * sizeof(float), stream);
    scatter_msg<<<scatterBlocks, 256, 0, stream>>>(x, e, src, dst, aggr, E);
    gemm_rowfull<true, true><<<nodeBlocks, 256, 0, stream>>>(
        x, aggr, W_conv + (size_t)(L - 1) * D * D, b_conv + (size_t)(L - 1) * D,
        node_feat, out, N);
}

// Round 3
// 3970.527 us; speedup vs baseline: 2.1646x; 2.1646x over previous
//
#include <hip/hip_runtime.h>

// GINEEncoderBlock — round 2: replace atomic scatter with CSR gather.
// R1 profile: 5x scatter_msg @1014us each (59% of 8.59ms), VALUBusy 1.4%,
// HBM 18.7% -> 76.8M f32 atomics are latency-bound, no pipe busy.
// Fix: build CSR over dst ONCE per launch (dst fixed), then gather-sum
// per node (one wave/node, regular loads, no f32 atomics).

#define D 256
#define BN_EPS 1e-5f

// ------------------------------------------------------------- CSR build ----
__global__ __launch_bounds__(256) void hist_kernel(
    const int* __restrict__ dst, int* __restrict__ cnt, int E)
{
    int i = blockIdx.x * 256 + threadIdx.x;
    if (i < E) atomicAdd(&cnt[dst[i]], 1);
}

// single-block inclusive scan -> row_ptr[1..N]; row_ptr[0]=0
__global__ __launch_bounds__(256) void scan_kernel(
    const int* __restrict__ cnt, int* __restrict__ row_ptr, int N)
{
    __shared__ int buf[256];
    __shared__ int carry_s;
    if (threadIdx.x == 0) { carry_s = 0; row_ptr[0] = 0; }
    __syncthreads();
    for (int base = 0; base < N; base += 256) {
        int i = base + threadIdx.x;
        int v = (i < N) ? cnt[i] : 0;
        buf[threadIdx.x] = v;
        __syncthreads();
#pragma unroll
        for (int off = 1; off < 256; off <<= 1) {
            int t = (threadIdx.x >= off) ? buf[threadIdx.x - off] : 0;
            __syncthreads();
            buf[threadIdx.x] += t;
            __syncthreads();
        }
        int inc = buf[threadIdx.x] + carry_s;
        if (i < N) row_ptr[i + 1] = inc;
        __syncthreads();
        if (threadIdx.x == 255) carry_s = inc;
        __syncthreads();
    }
}

__global__ __launch_bounds__(256) void fill_kernel(
    const int* __restrict__ dst, const int* __restrict__ row_ptr,
    int* __restrict__ fillc, int* __restrict__ edge_idx, int E)
{
    int i = blockIdx.x * 256 + threadIdx.x;
    if (i < E) {
        int d = dst[i];
        int pos = atomicAdd(&fillc[d], 1);
        edge_idx[row_ptr[d] + pos] = i;
    }
}

// ---------------------------------------------------------------- gather ----
// one wave per node; lane holds float4 (256 cols); sum relu(x[src]+e) over
// the node's incoming edges (CSR). Plain loads, single coalesced write.
__global__ __launch_bounds__(256) void gather_aggr(
    const float* __restrict__ x, const float* __restrict__ e,
    const int* __restrict__ src, const int* __restrict__ row_ptr,
    const int* __restrict__ edge_idx, float* __restrict__ aggr, int N)
{
    int node = blockIdx.x * 4 + (threadIdx.x >> 6);
    if (node >= N) return;
    int lane = threadIdx.x & 63;
    int beg = row_ptr[node], end = row_ptr[node + 1];
    float4 acc = make_float4(0.f, 0.f, 0.f, 0.f);
    for (int j = beg; j < end; ++j) {
        int ed = edge_idx[j];
        int s = src[ed];
        float4 ev = ((const float4*)(e + (size_t)ed * D))[lane];
        float4 xv = ((const float4*)(x + (size_t)s * D))[lane];
        acc.x += fmaxf(ev.x + xv.x, 0.f);
        acc.y += fmaxf(ev.y + xv.y, 0.f);
        acc.z += fmaxf(ev.z + xv.z, 0.f);
        acc.w += fmaxf(ev.w + xv.w, 0.f);
    }
    ((float4*)(aggr + (size_t)node * D))[lane] = acc;
}

// ------------------------------------------------------------------- GEMM ----
// Each block: 64 rows x FULL 256 cols (in-place safe: sole reader+writer of
// its rows). 256 thr = 16x16; thread computes 4 rows x 16 cols. K-chunk 16.
template<bool HAS_AGGR, bool ADD_INIT>
__global__ __launch_bounds__(256) void gemm_rowfull(
    const float* A, const float* __restrict__ aggr,
    const float* __restrict__ W, const float* __restrict__ bias,
    const float* __restrict__ init, float* out, int rows)
{
    __shared__ float As[16][68];
    __shared__ float Bs[16][260];

    const int tid = threadIdx.x;
    const int m0 = blockIdx.x * 64;
    const int tx = tid & 15;
    const int ty = tid >> 4;

    const int arow = tid >> 2;
    const int ak4  = (tid & 3) << 2;
    const int bk   = tid >> 4;
    const int bn4  = (tid & 15) << 2;

    float acc[4][16];
#pragma unroll
    for (int i = 0; i < 4; ++i)
#pragma unroll
        for (int j = 0; j < 16; ++j) acc[i][j] = 0.f;

    for (int k0 = 0; k0 < D; k0 += 16) {
        float4 av = make_float4(0.f, 0.f, 0.f, 0.f);
        int gr = m0 + arow;
        if (gr < rows) {
            av = *(const float4*)(A + (size_t)gr * D + k0 + ak4);
            if (HAS_AGGR) {
                float4 g = *(const float4*)(aggr + (size_t)gr * D + k0 + ak4);
                av.x += g.x; av.y += g.y; av.z += g.z; av.w += g.w;
            }
        }
        As[ak4 + 0][arow] = av.x;
        As[ak4 + 1][arow] = av.y;
        As[ak4 + 2][arow] = av.z;
        As[ak4 + 3][arow] = av.w;
#pragma unroll
        for (int c = 0; c < 4; ++c)
            *(float4*)&Bs[bk][c * 64 + bn4] =
                *(const float4*)(W + (size_t)(k0 + bk) * D + c * 64 + bn4);
        __syncthreads();
#pragma unroll
        for (int k = 0; k < 16; ++k) {
            float4 a4 = *(const float4*)&As[k][ty << 2];
            float a[4] = {a4.x, a4.y, a4.z, a4.w};
#pragma unroll
            for (int jc = 0; jc < 4; ++jc) {
                float4 b4 = *(const float4*)&Bs[k][(tx << 4) + (jc << 2)];
#pragma unroll
                for (int i = 0; i < 4; ++i) {
                    acc[i][jc * 4 + 0] += a[i] * b4.x;
                    acc[i][jc * 4 + 1] += a[i] * b4.y;
                    acc[i][jc * 4 + 2] += a[i] * b4.z;
                    acc[i][jc * 4 + 3] += a[i] * b4.w;
                }
            }
        }
        __syncthreads();
    }

#pragma unroll
    for (int jc = 0; jc < 4; ++jc) {
        int col = (tx << 4) + (jc << 2);
        float4 bias4 = *(const float4*)(bias + col);
#pragma unroll
        for (int i = 0; i < 4; ++i) {
            int gr = m0 + (ty << 2) + i;
            if (gr < rows) {
                float4 o;
                o.x = fmaxf(acc[i][jc * 4 + 0] + bias4.x, 0.f);
                o.y = fmaxf(acc[i][jc * 4 + 1] + bias4.y, 0.f);
                o.z = fmaxf(acc[i][jc * 4 + 2] + bias4.z, 0.f);
                o.w = fmaxf(acc[i][jc * 4 + 3] + bias4.w, 0.f);
                if (ADD_INIT) {
                    float4 iv = *(const float4*)(init + (size_t)gr * D + col);
                    o.x += iv.x; o.y += iv.y; o.z += iv.z; o.w += iv.w;
                }
                *(float4*)(out + (size_t)gr * D + col) = o;
            }
        }
    }
}

// --------------------------------------------------------------------- BN ----
__global__ __launch_bounds__(256) void bn_stats_kernel(
    const float* __restrict__ x, float* __restrict__ stats, int N)
{
    int col = threadIdx.x;
    float s = 0.f, s2 = 0.f;
    for (int r = blockIdx.x; r < N; r += gridDim.x) {
        float v = x[(size_t)r * D + col];
        s += v; s2 += v * v;
    }
    atomicAdd(&stats[col], s);
    atomicAdd(&stats[D + col], s2);
}

__global__ __launch_bounds__(256) void bn_apply_kernel(
    float* __restrict__ x, const float* __restrict__ stats,
    const float* __restrict__ gamma, const float* __restrict__ beta, int N)
{
    int col = threadIdx.x;
    float inv_n = 1.f / (float)N;
    float mean = stats[col] * inv_n;
    float var  = stats[D + col] * inv_n - mean * mean;
    float scale = gamma[col] * rsqrtf(var + BN_EPS);
    float shift = beta[col] - mean * scale;
    for (int r = blockIdx.x; r < N; r += gridDim.x) {
        size_t idx = (size_t)r * D + col;
        x[idx] = x[idx] * scale + shift;
    }
}

// ----------------------------------------------------------------- launch ----
extern "C" void kernel_launch(void* const* d_in, const int* in_sizes, int n_in,
                              void* d_out, int out_size, void* d_ws, size_t ws_size,
                              hipStream_t stream)
{
    const float* node_feat = (const float*)d_in[0];
    float*       e         = (float*)d_in[1];   // in place (harness restores)
    const int*   src       = (const int*)d_in[2];
    const int*   dst       = (const int*)d_in[3];
    const float* W_conv    = (const float*)d_in[4];
    const float* b_conv    = (const float*)d_in[5];
    const float* W_edge    = (const float*)d_in[6];
    const float* b_edge    = (const float*)d_in[7];
    const float* gamma     = (const float*)d_in[8];
    const float* beta      = (const float*)d_in[9];
    float*       out       = (float*)d_out;

    const int N = in_sizes[0] / D;
    const int E = in_sizes[2];
    const int L = in_sizes[5] / D;

    float* x        = (float*)d_ws;                  // N*D f32
    float* aggr     = x + (size_t)N * D;             // N*D f32
    float* stats    = aggr + (size_t)N * D;          // 2*D f32
    int*   cnt      = (int*)(stats + 2 * D);         // N
    int*   row_ptr  = cnt + N;                       // N+1
    int*   fillc    = row_ptr + N + 1;               // N
    int*   edge_idx = fillc + N;                     // E

    int nodeBlocks    = (N + 63) / 64;
    int edgeBlocks    = (E + 63) / 64;
    int gatherBlocks  = (N + 3) / 4;
    int eThreadBlocks = (E + 255) / 256;

    // ---- build CSR once (dst fixed for the whole call) ----
    hipMemsetAsync(cnt, 0, (size_t)N * sizeof(int), stream);
    hipMemsetAsync(fillc, 0, (size_t)N * sizeof(int), stream);
    hist_kernel<<<eThreadBlocks, 256, 0, stream>>>(dst, cnt, E);
    scan_kernel<<<1, 256, 0, stream>>>(cnt, row_ptr, N);
    fill_kernel<<<eThreadBlocks, 256, 0, stream>>>(dst, row_ptr, fillc, edge_idx, E);

    const float* xin = node_feat;
    for (int i = 0; i < L; ++i) {
        gather_aggr<<<gatherBlocks, 256, 0, stream>>>(
            xin, e, src, row_ptr, edge_idx, aggr, N);
        gemm_rowfull<true, false><<<nodeBlocks, 256, 0, stream>>>(
            xin, aggr, W_conv + (size_t)i * D * D, b_conv + (size_t)i * D,
            nullptr, x, N);
        hipMemsetAsync(stats, 0, 2 * D * sizeof(float), stream);
        bn_stats_kernel<<<512, 256, 0, stream>>>(x, stats, N);
        bn_apply_kernel<<<1024, 256, 0, stream>>>(
            x, stats, gamma + (size_t)i * D, beta + (size_t)i * D, N);
        gemm_rowfull<false, false><<<edgeBlocks, 256, 0, stream>>>(
            e, nullptr, W_edge + (size_t)i * D * D, b_edge + (size_t)i * D,
            nullptr, e, E);
        xin = x;
    }

    // final conv: layer L-1 weights on current (x, e), then + node_feat
    gather_aggr<<<gatherBlocks, 256, 0, stream>>>(
        x, e, src, row_ptr, edge_idx, aggr, N);
    gemm_rowfull<true, true><<<nodeBlocks, 256, 0, stream>>>(
        x, aggr, W_conv + (size_t)(L - 1) * D * D, b_conv + (size_t)(L - 1) * D,
        node_feat, out, N);
}